// Round 1
// baseline (497.655 us; speedup 1.0000x reference)
//
#include <hip/hip_runtime.h>
#include <hip/hip_bf16.h>

// Problem constants (fixed by reference): B=4, S=2048, DIN=DOUT=4096
constexpr int GM = 8192;   // B*S rows
constexpr int GN = 4096;   // DOUT
constexpr int GK = 4096;   // DIN

constexpr int BM = 128, BN = 128, BK = 64;

using bf16x8 = __attribute__((ext_vector_type(8))) __bf16;
using f32x4  = __attribute__((ext_vector_type(4))) float;

// -------------------- prep: A = bf16(x * in_scale) --------------------
__global__ __launch_bounds__(256) void prep_x_kernel(
    const float* __restrict__ x, const float* __restrict__ iscale,
    __bf16* __restrict__ A) {
  int e = (blockIdx.x * 256 + threadIdx.x) * 8;  // 8 elems/thread
  float4 v0 = *(const float4*)(x + e);
  float4 v1 = *(const float4*)(x + e + 4);
  int k = e & (GK - 1);
  float4 s0 = *(const float4*)(iscale + k);
  float4 s1 = *(const float4*)(iscale + k + 4);
  bf16x8 o;
  o[0] = (__bf16)(v0.x * s0.x);
  o[1] = (__bf16)(v0.y * s0.y);
  o[2] = (__bf16)(v0.z * s0.z);
  o[3] = (__bf16)(v0.w * s0.w);
  o[4] = (__bf16)(v1.x * s1.x);
  o[5] = (__bf16)(v1.y * s1.y);
  o[6] = (__bf16)(v1.z * s1.z);
  o[7] = (__bf16)(v1.w * s1.w);
  *(bf16x8*)(A + e) = o;
}

// -------------------- prep: Wb = bf16(sign(W)) --------------------
__device__ inline float sgnf(float v) {
  return (float)((v > 0.f) - (v < 0.f));
}

__global__ __launch_bounds__(256) void prep_w_kernel(
    const float* __restrict__ w, __bf16* __restrict__ Wb) {
  int e = (blockIdx.x * 256 + threadIdx.x) * 8;
  float4 v0 = *(const float4*)(w + e);
  float4 v1 = *(const float4*)(w + e + 4);
  bf16x8 o;
  o[0] = (__bf16)sgnf(v0.x);
  o[1] = (__bf16)sgnf(v0.y);
  o[2] = (__bf16)sgnf(v0.z);
  o[3] = (__bf16)sgnf(v0.w);
  o[4] = (__bf16)sgnf(v1.x);
  o[5] = (__bf16)sgnf(v1.y);
  o[6] = (__bf16)sgnf(v1.z);
  o[7] = (__bf16)sgnf(v1.w);
  *(bf16x8*)(Wb + e) = o;
}

// -------------------- GEMM: C[m][n] = sum_k A[m][k]*Wb[n][k] --------------------
__device__ inline void gload16(const __bf16* g, __bf16* l) {
  __builtin_amdgcn_global_load_lds(
      (const __attribute__((address_space(1))) void*)g,
      (__attribute__((address_space(3))) void*)l, 16, 0, 0);
}

__global__ __launch_bounds__(256) void gemm_bt(
    const __bf16* __restrict__ A, const __bf16* __restrict__ B,
    float* __restrict__ C) {
  __shared__ __align__(16) __bf16 sA[BM * BK];
  __shared__ __align__(16) __bf16 sB[BN * BK];

  // XCD-aware swizzle (grid=2048, divisible by 8 -> bijective)
  int bid = blockIdx.x;
  int swz = (bid & 7) * ((int)gridDim.x >> 3) + (bid >> 3);
  int brow = swz / (GN / BN);
  int bcol = swz % (GN / BN);

  int tid = threadIdx.x;
  int wid = tid >> 6;
  int lane = tid & 63;
  int wr = wid >> 1, wc = wid & 1;
  int lrow = lane & 15;  // fragment row/col within 16
  int lkhi = lane >> 4;  // 0..3 (k-slice / acc row group)

  const __bf16* Ab = A + (size_t)(brow * BM) * GK;
  const __bf16* Bb = B + (size_t)(bcol * BN) * GK;

  f32x4 acc[4][4] = {};

  for (int kt = 0; kt < GK / BK; ++kt) {
    int k0 = kt * BK;
    // stage A tile: 128x64 bf16 = 16KB, linear row-major, 4 issues x 4 waves x 1KB
#pragma unroll
    for (int i = 0; i < 4; ++i) {
      int e = i * 2048 + (wid * 64 + lane) * 8;  // element within tile
      int r = e >> 6, c = e & 63;
      gload16(Ab + (size_t)r * GK + k0 + c, &sA[i * 2048 + wid * 512]);
    }
#pragma unroll
    for (int i = 0; i < 4; ++i) {
      int e = i * 2048 + (wid * 64 + lane) * 8;
      int r = e >> 6, c = e & 63;
      gload16(Bb + (size_t)r * GK + k0 + c, &sB[i * 2048 + wid * 512]);
    }
    __syncthreads();  // compiler emits vmcnt(0) drain before barrier

#pragma unroll
    for (int kk = 0; kk < 2; ++kk) {
      bf16x8 av[4], bv[4];
#pragma unroll
      for (int mi = 0; mi < 4; ++mi)
        av[mi] = *(const bf16x8*)&sA[(wr * 64 + mi * 16 + lrow) * BK + kk * 32 + lkhi * 8];
#pragma unroll
      for (int ni = 0; ni < 4; ++ni)
        bv[ni] = *(const bf16x8*)&sB[(wc * 64 + ni * 16 + lrow) * BK + kk * 32 + lkhi * 8];
#pragma unroll
      for (int mi = 0; mi < 4; ++mi)
#pragma unroll
        for (int ni = 0; ni < 4; ++ni)
          acc[mi][ni] = __builtin_amdgcn_mfma_f32_16x16x32_bf16(
              av[mi], bv[ni], acc[mi][ni], 0, 0, 0);
    }
    __syncthreads();
  }

  // epilogue: C/D layout (16x16x32 bf16): col = lane&15, row = (lane>>4)*4 + r
  int crow0 = brow * BM + wr * 64;
  int ccol0 = bcol * BN + wc * 64;
#pragma unroll
  for (int mi = 0; mi < 4; ++mi)
#pragma unroll
    for (int ni = 0; ni < 4; ++ni) {
      int col = ccol0 + ni * 16 + lrow;
#pragma unroll
      for (int r = 0; r < 4; ++r) {
        int row = crow0 + mi * 16 + lkhi * 4 + r;
        C[(size_t)row * GN + col] = acc[mi][ni][r];
      }
    }
}

// -------------------- fused out_scale/bias + LayerNorm (in place) --------------------
__global__ __launch_bounds__(256) void ln_fuse(
    float* __restrict__ h, const float* __restrict__ os,
    const float* __restrict__ bs, const float* __restrict__ g,
    const float* __restrict__ be) {
  constexpr int N = GN;  // 4096
  int row = blockIdx.x;
  float* hr = h + (size_t)row * N;
  int t = threadIdx.x;

  float v[16];
  float sum = 0.f, ssq = 0.f;
#pragma unroll
  for (int c = 0; c < 4; ++c) {
    int idx = c * 1024 + t * 4;
    float4 hv = *(const float4*)(hr + idx);
    float4 sv = *(const float4*)(os + idx);
    float4 bv = *(const float4*)(bs + idx);
    float a0 = hv.x * sv.x + bv.x;
    float a1 = hv.y * sv.y + bv.y;
    float a2 = hv.z * sv.z + bv.z;
    float a3 = hv.w * sv.w + bv.w;
    v[c * 4 + 0] = a0; v[c * 4 + 1] = a1; v[c * 4 + 2] = a2; v[c * 4 + 3] = a3;
    sum += a0 + a1 + a2 + a3;
    ssq += a0 * a0 + a1 * a1 + a2 * a2 + a3 * a3;
  }

  // wave64 reduce
#pragma unroll
  for (int off = 32; off > 0; off >>= 1) {
    sum += __shfl_down(sum, off);
    ssq += __shfl_down(ssq, off);
  }
  __shared__ float rs[8];
  int wid = t >> 6, lane = t & 63;
  if (lane == 0) { rs[wid] = sum; rs[4 + wid] = ssq; }
  __syncthreads();
  sum = rs[0] + rs[1] + rs[2] + rs[3];
  ssq = rs[4] + rs[5] + rs[6] + rs[7];

  float mean = sum * (1.f / N);
  float var = ssq * (1.f / N) - mean * mean;
  float rstd = rsqrtf(var + 1e-5f);

#pragma unroll
  for (int c = 0; c < 4; ++c) {
    int idx = c * 1024 + t * 4;
    float4 gv = *(const float4*)(g + idx);
    float4 bev = *(const float4*)(be + idx);
    float4 o;
    o.x = (v[c * 4 + 0] - mean) * rstd * gv.x + bev.x;
    o.y = (v[c * 4 + 1] - mean) * rstd * gv.y + bev.y;
    o.z = (v[c * 4 + 2] - mean) * rstd * gv.z + bev.z;
    o.w = (v[c * 4 + 3] - mean) * rstd * gv.w + bev.w;
    *(float4*)(hr + idx) = o;
  }
}

extern "C" void kernel_launch(void* const* d_in, const int* in_sizes, int n_in,
                              void* d_out, int out_size, void* d_ws, size_t ws_size,
                              hipStream_t stream) {
  const float* x      = (const float*)d_in[0];  // [4,2048,4096]
  const float* w      = (const float*)d_in[1];  // [4096,4096]
  const float* iscale = (const float*)d_in[2];  // [4096]
  const float* oscale = (const float*)d_in[3];  // [4096]
  const float* bias   = (const float*)d_in[4];  // [4096]
  const float* gamma  = (const float*)d_in[5];  // [4096]
  const float* beta   = (const float*)d_in[6];  // [4096]
  float* out = (float*)d_out;                   // [8192,4096] f32

  __bf16* Abf = (__bf16*)d_ws;                                   // 67 MB
  __bf16* Wbf = (__bf16*)((char*)d_ws + (size_t)GM * GK * 2);    // 33.5 MB

  prep_x_kernel<<<(GM * GK) / (256 * 8), 256, 0, stream>>>(x, iscale, Abf);
  prep_w_kernel<<<(GN * GK) / (256 * 8), 256, 0, stream>>>(w, Wbf);
  gemm_bt<<<(GM / BM) * (GN / BN), 256, 0, stream>>>(Abf, Wbf, out);
  ln_fuse<<<GM, 256, 0, stream>>>(out, oscale, bias, gamma, beta);
}

// Round 2
// 416.373 us; speedup vs baseline: 1.1952x; 1.1952x over previous
//
#include <hip/hip_runtime.h>
#include <hip/hip_bf16.h>

// Problem constants (fixed by reference): B=4, S=2048, DIN=DOUT=4096
constexpr int GM = 8192;   // B*S rows
constexpr int GN = 4096;   // DOUT
constexpr int GK = 4096;   // DIN

constexpr int BM = 256, BN = 128, BK = 64;
constexpr int NT = GK / BK;                       // 64 K-tiles
constexpr int A_ELEMS = BM * BK;                  // 16384 bf16 per A tile
constexpr int B_ELEMS = BN * BK;                  // 8192 bf16 per B tile
constexpr int LDS_BYTES = 3 * (A_ELEMS + B_ELEMS) * 2;  // 147456 = 144 KiB

using bf16x8 = __attribute__((ext_vector_type(8))) __bf16;
using f32x4  = __attribute__((ext_vector_type(4))) float;

// -------------------- prep: A = bf16(x * in_scale) --------------------
__global__ __launch_bounds__(256) void prep_x_kernel(
    const float* __restrict__ x, const float* __restrict__ iscale,
    __bf16* __restrict__ A) {
  int e = (blockIdx.x * 256 + threadIdx.x) * 8;  // 8 elems/thread
  float4 v0 = *(const float4*)(x + e);
  float4 v1 = *(const float4*)(x + e + 4);
  int k = e & (GK - 1);
  float4 s0 = *(const float4*)(iscale + k);
  float4 s1 = *(const float4*)(iscale + k + 4);
  bf16x8 o;
  o[0] = (__bf16)(v0.x * s0.x);
  o[1] = (__bf16)(v0.y * s0.y);
  o[2] = (__bf16)(v0.z * s0.z);
  o[3] = (__bf16)(v0.w * s0.w);
  o[4] = (__bf16)(v1.x * s1.x);
  o[5] = (__bf16)(v1.y * s1.y);
  o[6] = (__bf16)(v1.z * s1.z);
  o[7] = (__bf16)(v1.w * s1.w);
  *(bf16x8*)(A + e) = o;
}

// -------------------- prep: Wb = bf16(sign(W)) --------------------
__device__ inline float sgnf(float v) {
  return (float)((v > 0.f) - (v < 0.f));
}

__global__ __launch_bounds__(256) void prep_w_kernel(
    const float* __restrict__ w, __bf16* __restrict__ Wb) {
  int e = (blockIdx.x * 256 + threadIdx.x) * 8;
  float4 v0 = *(const float4*)(w + e);
  float4 v1 = *(const float4*)(w + e + 4);
  bf16x8 o;
  o[0] = (__bf16)sgnf(v0.x);
  o[1] = (__bf16)sgnf(v0.y);
  o[2] = (__bf16)sgnf(v0.z);
  o[3] = (__bf16)sgnf(v0.w);
  o[4] = (__bf16)sgnf(v1.x);
  o[5] = (__bf16)sgnf(v1.y);
  o[6] = (__bf16)sgnf(v1.z);
  o[7] = (__bf16)sgnf(v1.w);
  *(bf16x8*)(Wb + e) = o;
}

// -------------------- GEMM: C[m][n] = sum_k A[m][k]*Wb[n][k] --------------------
// 256x128 tile, BK=64, 512 threads (8 waves = 4M x 2N), 3-deep LDS pipeline,
// counted vmcnt(6) (never 0 in steady state), 1 barrier per K-tile,
// XOR bank-conflict swizzle applied on BOTH sides (pre-swizzled global source
// for the linear global_load_lds dest + swizzled ds_read address).
__device__ inline void gload16(const __bf16* g, __bf16* l) {
  __builtin_amdgcn_global_load_lds(
      (const __attribute__((address_space(1))) void*)g,
      (__attribute__((address_space(3))) void*)l, 16, 0, 0);
}

__global__ __launch_bounds__(512, 2) void gemm_bt(
    const __bf16* __restrict__ A, const __bf16* __restrict__ B,
    float* __restrict__ C) {
  extern __shared__ __bf16 lds[];
  __bf16* sAb = lds;                 // 3 x 16384 bf16
  __bf16* sBb = lds + 3 * A_ELEMS;   // 3 x  8192 bf16

  // XCD-aware swizzle; grid = 1024 (divisible by 8 -> bijective).
  // bcol-major chunks: 32 co-resident blocks per XCD share one B panel (1 MB -> L2).
  int bid = blockIdx.x;
  int swz = (bid & 7) * ((GM / BM) * (GN / BN) / 8) + (bid >> 3);
  int bcol = swz >> 5;  // 0..31
  int brow = swz & 31;  // 0..31

  int tid = threadIdx.x, wid = tid >> 6, lane = tid & 63;
  int wm = wid >> 1, wn = wid & 1;     // wave -> 64x64 output sub-tile
  int lrow = lane & 15, lkhi = lane >> 4;
  int l8 = lane >> 3;                          // 0..7 (row-within-8 on stage)
  int srccol = ((lane & 7) ^ l8) * 8;          // pre-swizzled global source col (elems)
  int swx = (lane & 7) << 4;                   // read-side XOR (bytes); ==(row&7)<<4

  const __bf16* Ab = A + (size_t)(brow * BM) * GK;
  const __bf16* Bb = B + (size_t)(bcol * BN) * GK;

  f32x4 acc[4][4] = {};

  auto STAGE = [&](int kt, int bufi) {
    int k0 = kt * BK;
#pragma unroll
    for (int li = 0; li < 4; ++li)   // A: 256 rows, 8KB per issue
      gload16(Ab + (size_t)(li * 64 + wid * 8 + l8) * GK + k0 + srccol,
              sAb + bufi * A_ELEMS + li * 4096 + wid * 512);
#pragma unroll
    for (int li = 0; li < 2; ++li)   // B: 128 rows
      gload16(Bb + (size_t)(li * 64 + wid * 8 + l8) * GK + k0 + srccol,
              sBb + bufi * B_ELEMS + li * 4096 + wid * 512);
  };

  // prologue: tiles 0 and 1 in flight; drain tile 0 (6 newest stay in flight)
  STAGE(0, 0);
  STAGE(1, 1);
  asm volatile("s_waitcnt vmcnt(6)" ::: "memory");
  __builtin_amdgcn_s_barrier();

  int bc = 0, bs = 2;
  for (int t = 0; t < NT; ++t) {
    if (t + 2 < NT) STAGE(t + 2, bs);  // buffer bs was consumed at iter t-1

    const char* At = (const char*)(sAb + bc * A_ELEMS);
    const char* Bt = (const char*)(sBb + bc * B_ELEMS);
#pragma unroll
    for (int kk = 0; kk < 2; ++kk) {
      int cbx = ((kk * 64) | (lkhi * 16)) ^ swx;  // swizzled byte col within row
      bf16x8 av[4], bv[4];
#pragma unroll
      for (int mi = 0; mi < 4; ++mi)
        av[mi] = *(const bf16x8*)(At + (wm * 64 + mi * 16 + lrow) * 128 + cbx);
#pragma unroll
      for (int ni = 0; ni < 4; ++ni)
        bv[ni] = *(const bf16x8*)(Bt + (wn * 64 + ni * 16 + lrow) * 128 + cbx);
#pragma unroll
      for (int mi = 0; mi < 4; ++mi)
#pragma unroll
        for (int ni = 0; ni < 4; ++ni)
          acc[mi][ni] = __builtin_amdgcn_mfma_f32_16x16x32_bf16(
              av[mi], bv[ni], acc[mi][ni], 0, 0, 0);
    }

    // pin compute (incl. ds_reads) before the tile boundary, then ensure
    // tile t+1 landed (drain to the 6 loads of tile t+2 only — never 0
    // mid-loop) and recycle buffer bc for stage at iter t+1.
    __builtin_amdgcn_sched_barrier(0);
    if (t < NT - 1) {
      if (t + 2 < NT) asm volatile("s_waitcnt vmcnt(6)" ::: "memory");
      else            asm volatile("s_waitcnt vmcnt(0)" ::: "memory");
      __builtin_amdgcn_s_barrier();
    }
    bc = (bc == 2) ? 0 : bc + 1;
    bs = (bs == 2) ? 0 : bs + 1;
  }

  // epilogue: C/D layout (16x16x32 bf16): col = lane&15, row = (lane>>4)*4 + r
  int crow0 = brow * BM + wm * 64;
  int ccol0 = bcol * BN + wn * 64;
#pragma unroll
  for (int mi = 0; mi < 4; ++mi)
#pragma unroll
    for (int ni = 0; ni < 4; ++ni) {
      int col = ccol0 + ni * 16 + lrow;
#pragma unroll
      for (int r = 0; r < 4; ++r) {
        int row = crow0 + mi * 16 + lkhi * 4 + r;
        C[(size_t)row * GN + col] = acc[mi][ni][r];
      }
    }
}

// -------------------- fused out_scale/bias + LayerNorm (in place) --------------------
__global__ __launch_bounds__(256) void ln_fuse(
    float* __restrict__ h, const float* __restrict__ os,
    const float* __restrict__ bs, const float* __restrict__ g,
    const float* __restrict__ be) {
  constexpr int N = GN;  // 4096
  int row = blockIdx.x;
  float* hr = h + (size_t)row * N;
  int t = threadIdx.x;

  float v[16];
  float sum = 0.f, ssq = 0.f;
#pragma unroll
  for (int c = 0; c < 4; ++c) {
    int idx = c * 1024 + t * 4;
    float4 hv = *(const float4*)(hr + idx);
    float4 sv = *(const float4*)(os + idx);
    float4 bv = *(const float4*)(bs + idx);
    float a0 = hv.x * sv.x + bv.x;
    float a1 = hv.y * sv.y + bv.y;
    float a2 = hv.z * sv.z + bv.z;
    float a3 = hv.w * sv.w + bv.w;
    v[c * 4 + 0] = a0; v[c * 4 + 1] = a1; v[c * 4 + 2] = a2; v[c * 4 + 3] = a3;
    sum += a0 + a1 + a2 + a3;
    ssq += a0 * a0 + a1 * a1 + a2 * a2 + a3 * a3;
  }

  // wave64 reduce
#pragma unroll
  for (int off = 32; off > 0; off >>= 1) {
    sum += __shfl_down(sum, off);
    ssq += __shfl_down(ssq, off);
  }
  __shared__ float rs[8];
  int wid = t >> 6, lane = t & 63;
  if (lane == 0) { rs[wid] = sum; rs[4 + wid] = ssq; }
  __syncthreads();
  sum = rs[0] + rs[1] + rs[2] + rs[3];
  ssq = rs[4] + rs[5] + rs[6] + rs[7];

  float mean = sum * (1.f / N);
  float var = ssq * (1.f / N) - mean * mean;
  float rstd = rsqrtf(var + 1e-5f);

#pragma unroll
  for (int c = 0; c < 4; ++c) {
    int idx = c * 1024 + t * 4;
    float4 gv = *(const float4*)(g + idx);
    float4 bev = *(const float4*)(be + idx);
    float4 o;
    o.x = (v[c * 4 + 0] - mean) * rstd * gv.x + bev.x;
    o.y = (v[c * 4 + 1] - mean) * rstd * gv.y + bev.y;
    o.z = (v[c * 4 + 2] - mean) * rstd * gv.z + bev.z;
    o.w = (v[c * 4 + 3] - mean) * rstd * gv.w + bev.w;
    *(float4*)(hr + idx) = o;
  }
}

extern "C" void kernel_launch(void* const* d_in, const int* in_sizes, int n_in,
                              void* d_out, int out_size, void* d_ws, size_t ws_size,
                              hipStream_t stream) {
  const float* x      = (const float*)d_in[0];  // [4,2048,4096]
  const float* w      = (const float*)d_in[1];  // [4096,4096]
  const float* iscale = (const float*)d_in[2];  // [4096]
  const float* oscale = (const float*)d_in[3];  // [4096]
  const float* bias   = (const float*)d_in[4];  // [4096]
  const float* gamma  = (const float*)d_in[5];  // [4096]
  const float* beta   = (const float*)d_in[6];  // [4096]
  float* out = (float*)d_out;                   // [8192,4096] f32

  __bf16* Abf = (__bf16*)d_ws;                                   // 67 MB
  __bf16* Wbf = (__bf16*)((char*)d_ws + (size_t)GM * GK * 2);    // 33.5 MB

  // allow >64KB dynamic LDS (idempotent; immediate API, not graph-captured)
  (void)hipFuncSetAttribute((const void*)gemm_bt,
                            hipFuncAttributeMaxDynamicSharedMemorySize, LDS_BYTES);

  prep_x_kernel<<<(GM * GK) / (256 * 8), 256, 0, stream>>>(x, iscale, Abf);
  prep_w_kernel<<<(GN * GK) / (256 * 8), 256, 0, stream>>>(w, Wbf);
  gemm_bt<<<(GM / BM) * (GN / BN), 512, LDS_BYTES, stream>>>(Abf, Wbf, out);
  ln_fuse<<<GM, 256, 0, stream>>>(out, oscale, bias, gamma, beta);
}

// Round 3
// 312.885 us; speedup vs baseline: 1.5905x; 1.3308x over previous
//
#include <hip/hip_runtime.h>
#include <hip/hip_bf16.h>

// Problem constants (fixed by reference): B=4, S=2048, DIN=DOUT=4096
constexpr int GM = 8192;   // B*S rows
constexpr int GN = 4096;   // DOUT
constexpr int GK = 4096;   // DIN

constexpr int BM = 256, BN = 256, BK = 32;
constexpr int NT = GK / BK;                 // 128 K-tiles
constexpr int SLOT_BYTES = (BM + BN) * BK * 2;  // 32 KiB (A 16K + B 16K)
constexpr int LDS_BYTES = 3 * SLOT_BYTES;       // 96 KiB, 3-deep pipeline

using bf16x8 = __attribute__((ext_vector_type(8))) __bf16;
using f32x4  = __attribute__((ext_vector_type(4))) float;

// -------------------- prep: A = bf16(x * in_scale) --------------------
__global__ __launch_bounds__(256) void prep_x_kernel(
    const float* __restrict__ x, const float* __restrict__ iscale,
    __bf16* __restrict__ A) {
  int e = (blockIdx.x * 256 + threadIdx.x) * 8;  // 8 elems/thread
  float4 v0 = *(const float4*)(x + e);
  float4 v1 = *(const float4*)(x + e + 4);
  int k = e & (GK - 1);
  float4 s0 = *(const float4*)(iscale + k);
  float4 s1 = *(const float4*)(iscale + k + 4);
  bf16x8 o;
  o[0] = (__bf16)(v0.x * s0.x);
  o[1] = (__bf16)(v0.y * s0.y);
  o[2] = (__bf16)(v0.z * s0.z);
  o[3] = (__bf16)(v0.w * s0.w);
  o[4] = (__bf16)(v1.x * s1.x);
  o[5] = (__bf16)(v1.y * s1.y);
  o[6] = (__bf16)(v1.z * s1.z);
  o[7] = (__bf16)(v1.w * s1.w);
  *(bf16x8*)(A + e) = o;
}

// -------------------- prep: Wb = bf16(sign(W)) --------------------
__device__ inline float sgnf(float v) {
  return (float)((v > 0.f) - (v < 0.f));
}

__global__ __launch_bounds__(256) void prep_w_kernel(
    const float* __restrict__ w, __bf16* __restrict__ Wb) {
  int e = (blockIdx.x * 256 + threadIdx.x) * 8;
  float4 v0 = *(const float4*)(w + e);
  float4 v1 = *(const float4*)(w + e + 4);
  bf16x8 o;
  o[0] = (__bf16)sgnf(v0.x);
  o[1] = (__bf16)sgnf(v0.y);
  o[2] = (__bf16)sgnf(v0.z);
  o[3] = (__bf16)sgnf(v0.w);
  o[4] = (__bf16)sgnf(v1.x);
  o[5] = (__bf16)sgnf(v1.y);
  o[6] = (__bf16)sgnf(v1.z);
  o[7] = (__bf16)sgnf(v1.w);
  *(bf16x8*)(Wb + e) = o;
}

// -------------------- GEMM: C[m][n] = sum_k A[m][k]*Wb[n][k] --------------------
// 256x256 tile, BK=32, 512 threads (8 waves = 2M x 4N, wave tile 128x64).
// 3-deep LDS slot rotation (96 KiB): stage K-tile t+2 while computing t —
// race-free (slot was fully consumed at iter t-1, trailing barrier orders).
// Counted vmcnt(4) per K-tile (never 0 mid-loop). 2 sub-phases per K-tile
// (ni-halves, 16 MFMA each) with pre-MFMA barrier + setprio (T3/T4/T5).
// LDS rows are 64 B (BK=32); 16-B chunk c of row r holds K-group c^((r>>1)&3)
// so each 8-lane octet of a ds_read_b128 covers all 32 banks exactly once.
__device__ inline void gload16(const __bf16* g, const __bf16* l) {
  __builtin_amdgcn_global_load_lds(
      (const __attribute__((address_space(1))) void*)g,
      (__attribute__((address_space(3))) void*)l, 16, 0, 0);
}

__global__ __launch_bounds__(512, 2) void gemm_bt(
    const __bf16* __restrict__ A, const __bf16* __restrict__ B,
    float* __restrict__ C) {
  extern __shared__ __bf16 lds[];  // 3 slots x (A 8192 + B 8192 elems)

  // Square XCD chunking: XCD x owns an 8(brow) x 8(bcol) super-tile; its 32
  // co-resident blocks form an 8x4 sub-block -> per-XCD working set
  // 16 MB (A) + 8 MB (B); ideal HBM fetch ~270 MB total.
  int bid = blockIdx.x;            // 0..511, HW round-robins bid%8 across XCDs
  int x = bid & 7, idx = bid >> 3; // 64 blocks per XCD
  int brow = ((x & 3) << 3) | (idx & 7);   // 0..31
  int bcol = ((x >> 2) << 3) | (idx >> 3); // 0..15

  int tid = threadIdx.x, wid = tid >> 6, lane = tid & 63;
  int wm = wid & 1, wn = wid >> 1;         // 2M x 4N waves
  int lrow = lane & 15, lkhi = lane >> 4;
  int rchunk = lkhi ^ ((lrow >> 1) & 3);   // swizzled 16-B chunk on read
  int gchunk = (tid & 3) ^ ((tid >> 3) & 3);  // pre-swizzled K-group on stage

  const __bf16* Ab = A + (size_t)(brow * BM) * GK;
  const __bf16* Bb = B + (size_t)(bcol * BN) * GK;

  // per-lane LDS byte offsets within a slot (A at 0, B at 16 KiB)
  const int offA = (wm * 128 + lrow) * 64 + rchunk * 16;          // + mi*1024
  const int offB = 16384 + (wn * 64 + lrow) * 64 + rchunk * 16;   // + ni*1024

  f32x4 acc[8][4] = {};

  // stage one K-tile's A (2 issues) or B (2 issues) into slot si.
  // thread t writes LDS bytes [t*16,t*16+16) of each 8 KB region (linear,
  // wave-uniform base + lane*16); the global source K-group is pre-swizzled.
  auto STAGE_A = [&](int kt, int si) {
    const __bf16* src = Ab + (size_t)(tid >> 2) * GK + kt * BK + gchunk * 8;
    const __bf16* dst = lds + si * 16384 + tid * 8;
#pragma unroll
    for (int li = 0; li < 2; ++li)
      gload16(src + (size_t)(li * 128) * GK, dst + li * 4096);
  };
  auto STAGE_B = [&](int kt, int si) {
    const __bf16* src = Bb + (size_t)(tid >> 2) * GK + kt * BK + gchunk * 8;
    const __bf16* dst = lds + si * 16384 + 8192 + tid * 8;
#pragma unroll
    for (int li = 0; li < 2; ++li)
      gload16(src + (size_t)(li * 128) * GK, dst + li * 4096);
  };

  // prologue: tiles 0,1 staged; wait tile 0 (its 4 loads are the oldest)
  STAGE_A(0, 0); STAGE_B(0, 0);
  STAGE_A(1, 1); STAGE_B(1, 1);
  asm volatile("s_waitcnt vmcnt(4)" ::: "memory");
  __builtin_amdgcn_s_barrier();

  int bc = 0, bs = 2;
  for (int t = 0; t < NT; ++t) {
    const char* sl = (const char*)lds + bc * SLOT_BYTES;
    bf16x8 av[8], bv[4];

    // ---- sub-phase 0: stage A of tile t+2; read av[8], bv[0..1]; MFMA ni 0-1
    if (t + 2 < NT) STAGE_A(t + 2, bs);
#pragma unroll
    for (int mi = 0; mi < 8; ++mi)
      av[mi] = *(const bf16x8*)(sl + offA + mi * 1024);
#pragma unroll
    for (int ni = 0; ni < 2; ++ni)
      bv[ni] = *(const bf16x8*)(sl + offB + ni * 1024);
    __builtin_amdgcn_sched_barrier(0);
    __builtin_amdgcn_s_barrier();
    __builtin_amdgcn_s_setprio(1);
#pragma unroll
    for (int mi = 0; mi < 8; ++mi)
#pragma unroll
      for (int ni = 0; ni < 2; ++ni)
        acc[mi][ni] = __builtin_amdgcn_mfma_f32_16x16x32_bf16(
            av[mi], bv[ni], acc[mi][ni], 0, 0, 0);
    __builtin_amdgcn_s_setprio(0);

    // ---- sub-phase 1: stage B of tile t+2; read bv[2..3]; MFMA ni 2-3
    if (t + 2 < NT) STAGE_B(t + 2, bs);
#pragma unroll
    for (int ni = 2; ni < 4; ++ni)
      bv[ni] = *(const bf16x8*)(sl + offB + ni * 1024);
    __builtin_amdgcn_sched_barrier(0);
    __builtin_amdgcn_s_barrier();
    __builtin_amdgcn_s_setprio(1);
#pragma unroll
    for (int mi = 0; mi < 8; ++mi)
#pragma unroll
      for (int ni = 2; ni < 4; ++ni)
        acc[mi][ni] = __builtin_amdgcn_mfma_f32_16x16x32_bf16(
            av[mi], bv[ni], acc[mi][ni], 0, 0, 0);
    __builtin_amdgcn_s_setprio(0);

    // ---- tile boundary: ensure tile t+1 landed (all but newest 4 loads),
    // and order this tile's reads before iter t+1's stage into slot bc.
    __builtin_amdgcn_sched_barrier(0);
    if (t < NT - 1) {
      if (t + 2 < NT) asm volatile("s_waitcnt vmcnt(4)" ::: "memory");
      else            asm volatile("s_waitcnt vmcnt(0)" ::: "memory");
      __builtin_amdgcn_s_barrier();
    }
    bc = (bc == 2) ? 0 : bc + 1;
    bs = (bs == 2) ? 0 : bs + 1;
  }

  // epilogue: C/D layout (16x16x32 bf16): col = lane&15, row = (lane>>4)*4 + r
  int crow0 = brow * BM + wm * 128;
  int ccol0 = bcol * BN + wn * 64;
#pragma unroll
  for (int mi = 0; mi < 8; ++mi)
#pragma unroll
    for (int ni = 0; ni < 4; ++ni) {
      int col = ccol0 + ni * 16 + lrow;
#pragma unroll
      for (int r = 0; r < 4; ++r) {
        int row = crow0 + mi * 16 + lkhi * 4 + r;
        C[(size_t)row * GN + col] = acc[mi][ni][r];
      }
    }
}

// -------------------- fused out_scale/bias + LayerNorm (in place) --------------------
__global__ __launch_bounds__(256) void ln_fuse(
    float* __restrict__ h, const float* __restrict__ os,
    const float* __restrict__ bs, const float* __restrict__ g,
    const float* __restrict__ be) {
  constexpr int N = GN;  // 4096
  int row = blockIdx.x;
  float* hr = h + (size_t)row * N;
  int t = threadIdx.x;

  float v[16];
  float sum = 0.f, ssq = 0.f;
#pragma unroll
  for (int c = 0; c < 4; ++c) {
    int idx = c * 1024 + t * 4;
    float4 hv = *(const float4*)(hr + idx);
    float4 sv = *(const float4*)(os + idx);
    float4 bv = *(const float4*)(bs + idx);
    float a0 = hv.x * sv.x + bv.x;
    float a1 = hv.y * sv.y + bv.y;
    float a2 = hv.z * sv.z + bv.z;
    float a3 = hv.w * sv.w + bv.w;
    v[c * 4 + 0] = a0; v[c * 4 + 1] = a1; v[c * 4 + 2] = a2; v[c * 4 + 3] = a3;
    sum += a0 + a1 + a2 + a3;
    ssq += a0 * a0 + a1 * a1 + a2 * a2 + a3 * a3;
  }

  // wave64 reduce
#pragma unroll
  for (int off = 32; off > 0; off >>= 1) {
    sum += __shfl_down(sum, off);
    ssq += __shfl_down(ssq, off);
  }
  __shared__ float rs[8];
  int wid = t >> 6, lane = t & 63;
  if (lane == 0) { rs[wid] = sum; rs[4 + wid] = ssq; }
  __syncthreads();
  sum = rs[0] + rs[1] + rs[2] + rs[3];
  ssq = rs[4] + rs[5] + rs[6] + rs[7];

  float mean = sum * (1.f / N);
  float var = ssq * (1.f / N) - mean * mean;
  float rstd = rsqrtf(var + 1e-5f);

#pragma unroll
  for (int c = 0; c < 4; ++c) {
    int idx = c * 1024 + t * 4;
    float4 gv = *(const float4*)(g + idx);
    float4 bev = *(const float4*)(be + idx);
    float4 o;
    o.x = (v[c * 4 + 0] - mean) * rstd * gv.x + bev.x;
    o.y = (v[c * 4 + 1] - mean) * rstd * gv.y + bev.y;
    o.z = (v[c * 4 + 2] - mean) * rstd * gv.z + bev.z;
    o.w = (v[c * 4 + 3] - mean) * rstd * gv.w + bev.w;
    *(float4*)(hr + idx) = o;
  }
}

extern "C" void kernel_launch(void* const* d_in, const int* in_sizes, int n_in,
                              void* d_out, int out_size, void* d_ws, size_t ws_size,
                              hipStream_t stream) {
  const float* x      = (const float*)d_in[0];  // [4,2048,4096]
  const float* w      = (const float*)d_in[1];  // [4096,4096]
  const float* iscale = (const float*)d_in[2];  // [4096]
  const float* oscale = (const float*)d_in[3];  // [4096]
  const float* bias   = (const float*)d_in[4];  // [4096]
  const float* gamma  = (const float*)d_in[5];  // [4096]
  const float* beta   = (const float*)d_in[6];  // [4096]
  float* out = (float*)d_out;                   // [8192,4096] f32

  __bf16* Abf = (__bf16*)d_ws;                                   // 67 MB
  __bf16* Wbf = (__bf16*)((char*)d_ws + (size_t)GM * GK * 2);    // 33.5 MB

  // allow >64KB dynamic LDS (idempotent; immediate API, not graph-captured)
  (void)hipFuncSetAttribute((const void*)gemm_bt,
                            hipFuncAttributeMaxDynamicSharedMemorySize, LDS_BYTES);

  prep_x_kernel<<<(GM * GK) / (256 * 8), 256, 0, stream>>>(x, iscale, Abf);
  prep_w_kernel<<<(GN * GK) / (256 * 8), 256, 0, stream>>>(w, Wbf);
  gemm_bt<<<(GM / BM) * (GN / BN), 512, LDS_BYTES, stream>>>(Abf, Wbf, out);
  ln_fuse<<<GM, 256, 0, stream>>>(out, oscale, bias, gamma, beta);
}

// Round 4
// 310.243 us; speedup vs baseline: 1.6041x; 1.0085x over previous
//
#include <hip/hip_runtime.h>
#include <hip/hip_bf16.h>

// Problem constants (fixed by reference): B=4, S=2048, DIN=DOUT=4096
constexpr int GM = 8192;   // B*S rows
constexpr int GN = 4096;   // DOUT
constexpr int GK = 4096;   // DIN

constexpr int BM = 256, BN = 256, BK = 32;
constexpr int NT = GK / BK;                     // 128 K-tiles
constexpr int SLOT_ELEMS = (BM + BN) * BK;      // 16384 bf16 (A 8192 + B 8192)
constexpr int SLOT_BYTES = SLOT_ELEMS * 2;      // 32 KiB
constexpr int LDS_BYTES = 4 * SLOT_BYTES;       // 128 KiB, 4-slot pipeline

using bf16x8 = __attribute__((ext_vector_type(8))) __bf16;
using f32x4  = __attribute__((ext_vector_type(4))) float;

// -------------------- prep: A = bf16(x * in_scale) --------------------
__global__ __launch_bounds__(256) void prep_x_kernel(
    const float* __restrict__ x, const float* __restrict__ iscale,
    __bf16* __restrict__ A) {
  int e = (blockIdx.x * 256 + threadIdx.x) * 8;  // 8 elems/thread
  float4 v0 = *(const float4*)(x + e);
  float4 v1 = *(const float4*)(x + e + 4);
  int k = e & (GK - 1);
  float4 s0 = *(const float4*)(iscale + k);
  float4 s1 = *(const float4*)(iscale + k + 4);
  bf16x8 o;
  o[0] = (__bf16)(v0.x * s0.x);
  o[1] = (__bf16)(v0.y * s0.y);
  o[2] = (__bf16)(v0.z * s0.z);
  o[3] = (__bf16)(v0.w * s0.w);
  o[4] = (__bf16)(v1.x * s1.x);
  o[5] = (__bf16)(v1.y * s1.y);
  o[6] = (__bf16)(v1.z * s1.z);
  o[7] = (__bf16)(v1.w * s1.w);
  *(bf16x8*)(A + e) = o;
}

// -------------------- prep: Wb = bf16(sign(W)) --------------------
__device__ inline float sgnf(float v) {
  return (float)((v > 0.f) - (v < 0.f));
}

__global__ __launch_bounds__(256) void prep_w_kernel(
    const float* __restrict__ w, __bf16* __restrict__ Wb) {
  int e = (blockIdx.x * 256 + threadIdx.x) * 8;
  float4 v0 = *(const float4*)(w + e);
  float4 v1 = *(const float4*)(w + e + 4);
  bf16x8 o;
  o[0] = (__bf16)sgnf(v0.x);
  o[1] = (__bf16)sgnf(v0.y);
  o[2] = (__bf16)sgnf(v0.z);
  o[3] = (__bf16)sgnf(v0.w);
  o[4] = (__bf16)sgnf(v1.x);
  o[5] = (__bf16)sgnf(v1.y);
  o[6] = (__bf16)sgnf(v1.z);
  o[7] = (__bf16)sgnf(v1.w);
  *(bf16x8*)(Wb + e) = o;
}

// -------------------- GEMM: C[m][n] = sum_k A[m][k]*Wb[n][k] --------------------
// 256x256 tile, BK=32, 512 threads (8 waves = 2M x 4N, wave tile 128x64).
// Register-level frag prefetch one K-tile ahead: per iter,
//   STAGE(t+2) -> vmcnt(4) -> barrier -> issue 12 ds_reads(t+1, other reg set)
//   -> MFMA x32 on tile t's frags (already in registers).
// The ds_reads complete under the MFMA window (LDS pipe || MFMA pipe), the
// compiler's auto-lgkmcnt before next iter's MFMA never stalls. ONE barrier
// per K-tile. 4-slot LDS rotation (128 KiB) is required for slot-recycle
// safety: reads of slot s complete (compiler lgkm) before MFMA(t); the
// re-stage of s for tile t+4 at iter t+2 is separated from that completion
// by the iter t+1 barrier. With 3 slots there is no separating barrier.
// Counted vmcnt(4): only tile t+2's 4 loads stay in flight, never drained
// mid-loop. LDS rows 64 B; 16-B chunk c of row r holds K-group c^((r>>1)&3)
// (both-sides swizzle: pre-swizzled global source, same XOR on read) ->
// 0 bank conflicts (verified R3).
__device__ inline void gload16(const __bf16* g, const __bf16* l) {
  __builtin_amdgcn_global_load_lds(
      (const __attribute__((address_space(1))) void*)g,
      (__attribute__((address_space(3))) void*)l, 16, 0, 0);
}

__global__ __launch_bounds__(512, 2) void gemm_bt(
    const __bf16* __restrict__ A, const __bf16* __restrict__ B,
    float* __restrict__ C) {
  extern __shared__ __bf16 lds[];  // 4 slots x (A 8192 + B 8192 elems)

  // Square XCD chunking: XCD x owns an 8(brow) x 8(bcol) super-tile; its 32
  // co-resident blocks form an 8x4 sub-block -> per-XCD working set
  // 16 MB (A) + 8 MB (B); measured FETCH ~197 MB.
  int bid = blockIdx.x;            // 0..511, HW round-robins bid%8 across XCDs
  int x = bid & 7, idx = bid >> 3; // 64 blocks per XCD
  int brow = ((x & 3) << 3) | (idx & 7);   // 0..31
  int bcol = ((x >> 2) << 3) | (idx >> 3); // 0..15

  int tid = threadIdx.x, wid = tid >> 6, lane = tid & 63;
  int wm = wid & 1, wn = wid >> 1;         // 2M x 4N waves
  int lrow = lane & 15, lkhi = lane >> 4;
  int rchunk = lkhi ^ ((lrow >> 1) & 3);      // swizzled 16-B chunk on read
  int gchunk = (tid & 3) ^ ((tid >> 3) & 3);  // pre-swizzled K-group on stage

  const __bf16* Ab = A + (size_t)(brow * BM) * GK;
  const __bf16* Bb = B + (size_t)(bcol * BN) * GK;

  // per-lane LDS byte offsets within a slot (A at 0, B at 16 KiB)
  const int offA = (wm * 128 + lrow) * 64 + rchunk * 16;          // + mi*1024
  const int offB = 16384 + (wn * 64 + lrow) * 64 + rchunk * 16;   // + ni*1024

  f32x4 acc[8][4] = {};

  // stage one K-tile (A: 2 issues, B: 2 issues) into slot si.
  // thread t writes LDS bytes [t*16,t*16+16) of each 8 KB region (linear,
  // wave-uniform base + lane*16); the global source K-group is pre-swizzled.
  auto STAGE = [&](int kt, int si) {
    const __bf16* srcA = Ab + (size_t)(tid >> 2) * GK + kt * BK + gchunk * 8;
    const __bf16* dstA = lds + si * SLOT_ELEMS + tid * 8;
    gload16(srcA, dstA);
    gload16(srcA + (size_t)128 * GK, dstA + 4096);
    const __bf16* srcB = Bb + (size_t)(tid >> 2) * GK + kt * BK + gchunk * 8;
    gload16(srcB, dstA + 8192);
    gload16(srcB + (size_t)128 * GK, dstA + 8192 + 4096);
  };

  auto LOADFRAGS = [&](int slot, bf16x8 (&av)[8], bf16x8 (&bv)[4]) {
    const char* sl = (const char*)lds + slot * SLOT_BYTES;
#pragma unroll
    for (int mi = 0; mi < 8; ++mi)
      av[mi] = *(const bf16x8*)(sl + offA + mi * 1024);
#pragma unroll
    for (int ni = 0; ni < 4; ++ni)
      bv[ni] = *(const bf16x8*)(sl + offB + ni * 1024);
  };

  auto MFMAS = [&](const bf16x8 (&av)[8], const bf16x8 (&bv)[4]) {
    __builtin_amdgcn_s_setprio(1);
#pragma unroll
    for (int mi = 0; mi < 8; ++mi)
#pragma unroll
      for (int ni = 0; ni < 4; ++ni)
        acc[mi][ni] = __builtin_amdgcn_mfma_f32_16x16x32_bf16(
            av[mi], bv[ni], acc[mi][ni], 0, 0, 0);
    __builtin_amdgcn_s_setprio(0);
  };

  bf16x8 avA[8], bvA[4], avB[8], bvB[4];

  // prologue: stage tiles 0,1; ensure tile 0 landed; preload tile-0 frags.
  STAGE(0, 0);
  STAGE(1, 1);
  asm volatile("s_waitcnt vmcnt(4)" ::: "memory");  // tile0 landed; tile1 in flight
  __builtin_amdgcn_s_barrier();
  __builtin_amdgcn_sched_barrier(0);
  LOADFRAGS(0, avA, bvA);
  __builtin_amdgcn_sched_barrier(0);

  for (int t = 0; t < NT; t += 2) {
    // ---- even iter: compute tile t (set A), prefetch frags of t+1 (set B)
    if (t + 2 < NT) STAGE(t + 2, (t + 2) & 3);
    __builtin_amdgcn_sched_barrier(0);
    if (t + 2 < NT) asm volatile("s_waitcnt vmcnt(4)" ::: "memory");
    else            asm volatile("s_waitcnt vmcnt(0)" ::: "memory");
    __builtin_amdgcn_s_barrier();   // everyone's tile t+1 landed
    __builtin_amdgcn_sched_barrier(0);
    LOADFRAGS((t + 1) & 3, avB, bvB);        // t+1 < NT always (NT even)
    __builtin_amdgcn_sched_barrier(0);
    MFMAS(avA, bvA);

    // ---- odd iter: compute tile t+1 (set B), prefetch frags of t+2 (set A)
    if (t + 3 < NT) STAGE(t + 3, (t + 3) & 3);
    __builtin_amdgcn_sched_barrier(0);
    if (t + 3 < NT) asm volatile("s_waitcnt vmcnt(4)" ::: "memory");
    else            asm volatile("s_waitcnt vmcnt(0)" ::: "memory");
    __builtin_amdgcn_s_barrier();   // everyone's tile t+2 landed
    __builtin_amdgcn_sched_barrier(0);
    if (t + 2 < NT) LOADFRAGS((t + 2) & 3, avA, bvA);
    __builtin_amdgcn_sched_barrier(0);
    MFMAS(avB, bvB);
  }

  // epilogue: C/D layout (16x16x32 bf16): col = lane&15, row = (lane>>4)*4 + r
  int crow0 = brow * BM + wm * 128;
  int ccol0 = bcol * BN + wn * 64;
#pragma unroll
  for (int mi = 0; mi < 8; ++mi)
#pragma unroll
    for (int ni = 0; ni < 4; ++ni) {
      int col = ccol0 + ni * 16 + lrow;
#pragma unroll
      for (int r = 0; r < 4; ++r) {
        int row = crow0 + mi * 16 + lkhi * 4 + r;
        C[(size_t)row * GN + col] = acc[mi][ni][r];
      }
    }
}

// -------------------- fused out_scale/bias + LayerNorm (in place) --------------------
__global__ __launch_bounds__(256) void ln_fuse(
    float* __restrict__ h, const float* __restrict__ os,
    const float* __restrict__ bs, const float* __restrict__ g,
    const float* __restrict__ be) {
  constexpr int N = GN;  // 4096
  int row = blockIdx.x;
  float* hr = h + (size_t)row * N;
  int t = threadIdx.x;

  float v[16];
  float sum = 0.f, ssq = 0.f;
#pragma unroll
  for (int c = 0; c < 4; ++c) {
    int idx = c * 1024 + t * 4;
    float4 hv = *(const float4*)(hr + idx);
    float4 sv = *(const float4*)(os + idx);
    float4 bv = *(const float4*)(bs + idx);
    float a0 = hv.x * sv.x + bv.x;
    float a1 = hv.y * sv.y + bv.y;
    float a2 = hv.z * sv.z + bv.z;
    float a3 = hv.w * sv.w + bv.w;
    v[c * 4 + 0] = a0; v[c * 4 + 1] = a1; v[c * 4 + 2] = a2; v[c * 4 + 3] = a3;
    sum += a0 + a1 + a2 + a3;
    ssq += a0 * a0 + a1 * a1 + a2 * a2 + a3 * a3;
  }

  // wave64 reduce
#pragma unroll
  for (int off = 32; off > 0; off >>= 1) {
    sum += __shfl_down(sum, off);
    ssq += __shfl_down(ssq, off);
  }
  __shared__ float rs[8];
  int wid = t >> 6, lane = t & 63;
  if (lane == 0) { rs[wid] = sum; rs[4 + wid] = ssq; }
  __syncthreads();
  sum = rs[0] + rs[1] + rs[2] + rs[3];
  ssq = rs[4] + rs[5] + rs[6] + rs[7];

  float mean = sum * (1.f / N);
  float var = ssq * (1.f / N) - mean * mean;
  float rstd = rsqrtf(var + 1e-5f);

#pragma unroll
  for (int c = 0; c < 4; ++c) {
    int idx = c * 1024 + t * 4;
    float4 gv = *(const float4*)(g + idx);
    float4 bev = *(const float4*)(be + idx);
    float4 o;
    o.x = (v[c * 4 + 0] - mean) * rstd * gv.x + bev.x;
    o.y = (v[c * 4 + 1] - mean) * rstd * gv.y + bev.y;
    o.z = (v[c * 4 + 2] - mean) * rstd * gv.z + bev.z;
    o.w = (v[c * 4 + 3] - mean) * rstd * gv.w + bev.w;
    *(float4*)(hr + idx) = o;
  }
}

extern "C" void kernel_launch(void* const* d_in, const int* in_sizes, int n_in,
                              void* d_out, int out_size, void* d_ws, size_t ws_size,
                              hipStream_t stream) {
  const float* x      = (const float*)d_in[0];  // [4,2048,4096]
  const float* w      = (const float*)d_in[1];  // [4096,4096]
  const float* iscale = (const float*)d_in[2];  // [4096]
  const float* oscale = (const float*)d_in[3];  // [4096]
  const float* bias   = (const float*)d_in[4];  // [4096]
  const float* gamma  = (const float*)d_in[5];  // [4096]
  const float* beta   = (const float*)d_in[6];  // [4096]
  float* out = (float*)d_out;                   // [8192,4096] f32

  __bf16* Abf = (__bf16*)d_ws;                                   // 67 MB
  __bf16* Wbf = (__bf16*)((char*)d_ws + (size_t)GM * GK * 2);    // 33.5 MB

  // allow >64KB dynamic LDS (idempotent; immediate API, not graph-captured)
  (void)hipFuncSetAttribute((const void*)gemm_bt,
                            hipFuncAttributeMaxDynamicSharedMemorySize, LDS_BYTES);

  prep_x_kernel<<<(GM * GK) / (256 * 8), 256, 0, stream>>>(x, iscale, Abf);
  prep_w_kernel<<<(GN * GK) / (256 * 8), 256, 0, stream>>>(w, Wbf);
  gemm_bt<<<(GM / BM) * (GN / BN), 512, LDS_BYTES, stream>>>(Abf, Wbf, out);
  ln_fuse<<<GM, 256, 0, stream>>>(out, oscale, bias, gamma, beta);
}

// Round 5
// 307.025 us; speedup vs baseline: 1.6209x; 1.0105x over previous
//
#include <hip/hip_runtime.h>
#include <hip/hip_bf16.h>

// Problem constants (fixed by reference): B=4, S=2048, DIN=DOUT=4096
constexpr int GM = 8192;   // B*S rows
constexpr int GN = 4096;   // DOUT
constexpr int GK = 4096;   // DIN

constexpr int BM = 256, BN = 256, BK = 64;
constexpr int NSTEP = GK / BK;   // 64 K-steps
constexpr int IT = NSTEP / 2;    // 32 iterations, 2 K-steps each
constexpr int LDS_BYTES = 2 * (BM + BN) * BK * 2;  // 131072 = 128 KiB

using bf16x8 = __attribute__((ext_vector_type(8))) __bf16;
using f32x4  = __attribute__((ext_vector_type(4))) float;

// -------------------- prep: A = bf16(x * in_scale) --------------------
__global__ __launch_bounds__(256) void prep_x_kernel(
    const float* __restrict__ x, const float* __restrict__ iscale,
    __bf16* __restrict__ A) {
  int e = (blockIdx.x * 256 + threadIdx.x) * 8;  // 8 elems/thread
  float4 v0 = *(const float4*)(x + e);
  float4 v1 = *(const float4*)(x + e + 4);
  int k = e & (GK - 1);
  float4 s0 = *(const float4*)(iscale + k);
  float4 s1 = *(const float4*)(iscale + k + 4);
  bf16x8 o;
  o[0] = (__bf16)(v0.x * s0.x);
  o[1] = (__bf16)(v0.y * s0.y);
  o[2] = (__bf16)(v0.z * s0.z);
  o[3] = (__bf16)(v0.w * s0.w);
  o[4] = (__bf16)(v1.x * s1.x);
  o[5] = (__bf16)(v1.y * s1.y);
  o[6] = (__bf16)(v1.z * s1.z);
  o[7] = (__bf16)(v1.w * s1.w);
  *(bf16x8*)(A + e) = o;
}

// -------------------- prep: Wb = bf16(sign(W)) --------------------
__device__ inline float sgnf(float v) {
  return (float)((v > 0.f) - (v < 0.f));
}

__global__ __launch_bounds__(256) void prep_w_kernel(
    const float* __restrict__ w, __bf16* __restrict__ Wb) {
  int e = (blockIdx.x * 256 + threadIdx.x) * 8;
  float4 v0 = *(const float4*)(w + e);
  float4 v1 = *(const float4*)(w + e + 4);
  bf16x8 o;
  o[0] = (__bf16)sgnf(v0.x);
  o[1] = (__bf16)sgnf(v0.y);
  o[2] = (__bf16)sgnf(v0.z);
  o[3] = (__bf16)sgnf(v0.w);
  o[4] = (__bf16)sgnf(v1.x);
  o[5] = (__bf16)sgnf(v1.y);
  o[6] = (__bf16)sgnf(v1.z);
  o[7] = (__bf16)sgnf(v1.w);
  *(bf16x8*)(Wb + e) = o;
}

// -------------------- GEMM: C[m][n] = sum_k A[m][k]*Wb[n][k] --------------------
// m201-style 8-phase schedule. 256x256 tile, BK=64, 512 threads (2M x 4N
// waves, wave tile 128x64). LDS: 2 buffers x [A0|A1|B0|B1] x 16 KiB = 128 KiB.
// Per iteration (2 K-steps: even->buf0, odd->buf1), 8 phases; each phase:
//   [0-12 ds_read_b128] [1 half-tile stage = 2 gload_lds] sched_barrier
//   s_barrier; lgkmcnt(0); sched_barrier; setprio(1); 16 MFMA (one
//   C-quadrant x K=64); setprio(0); sched_barrier; s_barrier
// Counted vmcnt(4) ONLY at P4/P8 (before the barrier), never 0 mid-loop.
// Region-overwrite safety: all ds_reads of a region are issued >=1 phase
// before its re-stage, and each wave drains its reads (lgkmcnt 0) before its
// MFMA, hence before barrier-2 of that phase — so by the time any wave
// issues the re-stage, every wave's reads completed (two-barrier invariant).
// Swizzle (both sides): 16-B chunk p of row r holds K-group p^(r&7); the
// stage pre-permutes the global source column, reads XOR the chunk index.
__device__ inline void gload16(const __bf16* g, const __bf16* l) {
  __builtin_amdgcn_global_load_lds(
      (const __attribute__((address_space(1))) void*)g,
      (__attribute__((address_space(3))) void*)l, 16, 0, 0);
}

#define PHASE_SYNC()                                    \
  __builtin_amdgcn_sched_barrier(0);                    \
  __builtin_amdgcn_s_barrier();                         \
  asm volatile("s_waitcnt lgkmcnt(0)" ::: "memory");    \
  __builtin_amdgcn_sched_barrier(0);                    \
  __builtin_amdgcn_s_setprio(1);

#define PHASE_END()                                     \
  __builtin_amdgcn_s_setprio(0);                        \
  __builtin_amdgcn_sched_barrier(0);                    \
  __builtin_amdgcn_s_barrier();

#define QUAD(AV, BV, MO, NO)                                                 \
  {                                                                          \
    _Pragma("unroll") for (int mi = 0; mi < 4; ++mi)                         \
      _Pragma("unroll") for (int ni = 0; ni < 2; ++ni)                       \
        _Pragma("unroll") for (int kk = 0; kk < 2; ++kk)                     \
            acc[(MO) + mi][(NO) + ni] =                                      \
                __builtin_amdgcn_mfma_f32_16x16x32_bf16(                     \
                    AV[mi][kk], BV[ni][kk], acc[(MO) + mi][(NO) + ni],       \
                    0, 0, 0);                                                \
  }

__global__ __launch_bounds__(512, 2) void gemm_bt(
    const __bf16* __restrict__ A, const __bf16* __restrict__ B,
    float* __restrict__ C) {
  extern __shared__ __bf16 lds[];  // 2 x 64 KiB buffers

  // Square XCD chunking (FETCH ~200 MB measured in R3/R4)
  int bid = blockIdx.x;            // 0..511
  int x = bid & 7, idx = bid >> 3;
  int brow = ((x & 3) << 3) | (idx & 7);   // 0..31
  int bcol = ((x >> 2) << 3) | (idx >> 3); // 0..15

  int tid = threadIdx.x, wid = tid >> 6, lane = tid & 63;
  int wm = wid & 1, wn = wid >> 1;         // 2M x 4N waves
  int lrow = lane & 15, lkhi = lane >> 4;

  const __bf16* Ab = A + (size_t)(brow * BM) * GK;
  const __bf16* Bb = B + (size_t)(bcol * BN) * GK;
  const __bf16* Ab1 = Ab + (size_t)128 * GK;
  const __bf16* Bb1 = Bb + (size_t)128 * GK;

  // read-side swizzled chunk offsets (bytes within the 128-B row)
  int xr = lrow & 7;
  int offk0 = (lkhi ^ xr) * 16;        // kk=0 chunk
  int offk1 = ((4 + lkhi) ^ xr) * 16;  // kk=1 chunk
  const char* ldsc = (const char*)lds;
  // fragment byte bases within a buffer (regions: A0 0, A1 16K, B0 32K, B1 48K)
  int avbase = wm * 16384 + lrow * 128;                                // +mi*2048
  int bvbase = 32768 + (wn >> 1) * 16384 + ((wn & 1) * 64 + lrow) * 128;  // +ni*2048

  // stage-side: thread t writes bytes [t*16,t*16+16) of each 8-KiB half-region
  int grow = tid >> 3;                         // row within 64-row half
  int gcol = ((tid & 7) ^ (grow & 7)) * 8;     // pre-swizzled source col (elems)

  auto STAGE = [&](const __bf16* srcbase, int kstep, int dstelem) {
    const __bf16* s = srcbase + (size_t)grow * GK + kstep * BK + gcol;
    const __bf16* d = lds + dstelem + tid * 8;
    gload16(s, d);
    gload16(s + (size_t)64 * GK, d + 4096);
  };

  f32x4 acc[8][4] = {};

  // prologue: buf0 <- step0 (all 4 half-tiles); buf1 <- step1 A halves
  STAGE(Ab, 0, 0);
  STAGE(Ab1, 0, 8192);
  STAGE(Bb, 0, 16384);
  STAGE(Bb1, 0, 24576);
  STAGE(Ab, 1, 32768);
  STAGE(Ab1, 1, 40960);
  asm volatile("s_waitcnt vmcnt(4)" ::: "memory");  // buf0 landed
  __builtin_amdgcn_s_barrier();

  for (int i = 0; i < IT; ++i) {
    int s1 = 2 * i + 1, s2 = 2 * i + 2, s3 = 2 * i + 3;
    bool full = (i < IT - 1);
    bf16x8 a0[4][2], a4[4][2], b0[2][2], b2[2][2];

    // ================= K-step 2i (buf0, byte 0) =================
    // P1: read av0-3 + bv0-1 (12); stage s1:B0 -> buf1
#pragma unroll
    for (int mi = 0; mi < 4; ++mi) {
      a0[mi][0] = *(const bf16x8*)(ldsc + avbase + mi * 2048 + offk0);
      a0[mi][1] = *(const bf16x8*)(ldsc + avbase + mi * 2048 + offk1);
    }
#pragma unroll
    for (int ni = 0; ni < 2; ++ni) {
      b0[ni][0] = *(const bf16x8*)(ldsc + bvbase + ni * 2048 + offk0);
      b0[ni][1] = *(const bf16x8*)(ldsc + bvbase + ni * 2048 + offk1);
    }
    STAGE(Bb, s1, 49152);
    PHASE_SYNC();
    QUAD(a0, b0, 0, 0);
    PHASE_END();

    // P2: read av4-7 + bv2-3 (12); stage s1:B1 -> buf1
#pragma unroll
    for (int mi = 0; mi < 4; ++mi) {
      a4[mi][0] = *(const bf16x8*)(ldsc + avbase + (4 + mi) * 2048 + offk0);
      a4[mi][1] = *(const bf16x8*)(ldsc + avbase + (4 + mi) * 2048 + offk1);
    }
#pragma unroll
    for (int ni = 0; ni < 2; ++ni) {
      b2[ni][0] = *(const bf16x8*)(ldsc + bvbase + (2 + ni) * 2048 + offk0);
      b2[ni][1] = *(const bf16x8*)(ldsc + bvbase + (2 + ni) * 2048 + offk1);
    }
    STAGE(Bb1, s1, 57344);
    PHASE_SYNC();
    QUAD(a0, b2, 0, 2);
    PHASE_END();

    // P3: stage s2:A0 -> buf0 (its reads completed by P2's barrier-2)
    if (full) STAGE(Ab, s2, 0);
    PHASE_SYNC();
    QUAD(a4, b0, 4, 0);
    PHASE_END();

    // P4: stage s2:A1 -> buf0; counted vmcnt (ensures s1 fully landed)
    if (full) STAGE(Ab1, s2, 8192);
    PHASE_SYNC();
    QUAD(a4, b2, 4, 2);
    __builtin_amdgcn_s_setprio(0);
    __builtin_amdgcn_sched_barrier(0);
    if (full) asm volatile("s_waitcnt vmcnt(4)" ::: "memory");
    else      asm volatile("s_waitcnt vmcnt(0)" ::: "memory");
    __builtin_amdgcn_s_barrier();

    // ================= K-step 2i+1 (buf1, byte 65536) =================
    // P5: read av0-3 + bv0-1 (12); stage s2:B0 -> buf0
#pragma unroll
    for (int mi = 0; mi < 4; ++mi) {
      a0[mi][0] = *(const bf16x8*)(ldsc + 65536 + avbase + mi * 2048 + offk0);
      a0[mi][1] = *(const bf16x8*)(ldsc + 65536 + avbase + mi * 2048 + offk1);
    }
#pragma unroll
    for (int ni = 0; ni < 2; ++ni) {
      b0[ni][0] = *(const bf16x8*)(ldsc + 65536 + bvbase + ni * 2048 + offk0);
      b0[ni][1] = *(const bf16x8*)(ldsc + 65536 + bvbase + ni * 2048 + offk1);
    }
    if (full) STAGE(Bb, s2, 16384);
    PHASE_SYNC();
    QUAD(a0, b0, 0, 0);
    PHASE_END();

    // P6: read av4-7 + bv2-3 (12); stage s2:B1 -> buf0
#pragma unroll
    for (int mi = 0; mi < 4; ++mi) {
      a4[mi][0] = *(const bf16x8*)(ldsc + 65536 + avbase + (4 + mi) * 2048 + offk0);
      a4[mi][1] = *(const bf16x8*)(ldsc + 65536 + avbase + (4 + mi) * 2048 + offk1);
    }
#pragma unroll
    for (int ni = 0; ni < 2; ++ni) {
      b2[ni][0] = *(const bf16x8*)(ldsc + 65536 + bvbase + (2 + ni) * 2048 + offk0);
      b2[ni][1] = *(const bf16x8*)(ldsc + 65536 + bvbase + (2 + ni) * 2048 + offk1);
    }
    if (full) STAGE(Bb1, s2, 24576);
    PHASE_SYNC();
    QUAD(a0, b2, 0, 2);
    PHASE_END();

    // P7: stage s3:A0 -> buf1 (reads of buf1-A completed by P6's barrier-2)
    if (full) STAGE(Ab, s3, 32768);
    PHASE_SYNC();
    QUAD(a4, b0, 4, 0);
    PHASE_END();

    // P8: stage s3:A1 -> buf1; counted vmcnt (ensures s2 fully landed)
    if (full) STAGE(Ab1, s3, 40960);
    PHASE_SYNC();
    QUAD(a4, b2, 4, 2);
    __builtin_amdgcn_s_setprio(0);
    __builtin_amdgcn_sched_barrier(0);
    if (full) asm volatile("s_waitcnt vmcnt(4)" ::: "memory");
    else      asm volatile("s_waitcnt vmcnt(0)" ::: "memory");
    __builtin_amdgcn_s_barrier();
  }

  // epilogue: C/D layout (16x16x32 bf16): col = lane&15, row = (lane>>4)*4 + r
  int crow0 = brow * BM + wm * 128;
  int ccol0 = bcol * BN + wn * 64;
#pragma unroll
  for (int mi = 0; mi < 8; ++mi)
#pragma unroll
    for (int ni = 0; ni < 4; ++ni) {
      int col = ccol0 + ni * 16 + lrow;
#pragma unroll
      for (int r = 0; r < 4; ++r) {
        int row = crow0 + mi * 16 + lkhi * 4 + r;
        C[(size_t)row * GN + col] = acc[mi][ni][r];
      }
    }
}

// -------------------- fused out_scale/bias + LayerNorm (in place) --------------------
__global__ __launch_bounds__(256) void ln_fuse(
    float* __restrict__ h, const float* __restrict__ os,
    const float* __restrict__ bs, const float* __restrict__ g,
    const float* __restrict__ be) {
  constexpr int N = GN;  // 4096
  int row = blockIdx.x;
  float* hr = h + (size_t)row * N;
  int t = threadIdx.x;

  float v[16];
  float sum = 0.f, ssq = 0.f;
#pragma unroll
  for (int c = 0; c < 4; ++c) {
    int idx = c * 1024 + t * 4;
    float4 hv = *(const float4*)(hr + idx);
    float4 sv = *(const float4*)(os + idx);
    float4 bv = *(const float4*)(bs + idx);
    float a0 = hv.x * sv.x + bv.x;
    float a1 = hv.y * sv.y + bv.y;
    float a2 = hv.z * sv.z + bv.z;
    float a3 = hv.w * sv.w + bv.w;
    v[c * 4 + 0] = a0; v[c * 4 + 1] = a1; v[c * 4 + 2] = a2; v[c * 4 + 3] = a3;
    sum += a0 + a1 + a2 + a3;
    ssq += a0 * a0 + a1 * a1 + a2 * a2 + a3 * a3;
  }

  // wave64 reduce
#pragma unroll
  for (int off = 32; off > 0; off >>= 1) {
    sum += __shfl_down(sum, off);
    ssq += __shfl_down(ssq, off);
  }
  __shared__ float rs[8];
  int wid = t >> 6, lane = t & 63;
  if (lane == 0) { rs[wid] = sum; rs[4 + wid] = ssq; }
  __syncthreads();
  sum = rs[0] + rs[1] + rs[2] + rs[3];
  ssq = rs[4] + rs[5] + rs[6] + rs[7];

  float mean = sum * (1.f / N);
  float var = ssq * (1.f / N) - mean * mean;
  float rstd = rsqrtf(var + 1e-5f);

#pragma unroll
  for (int c = 0; c < 4; ++c) {
    int idx = c * 1024 + t * 4;
    float4 gv = *(const float4*)(g + idx);
    float4 bev = *(const float4*)(be + idx);
    float4 o;
    o.x = (v[c * 4 + 0] - mean) * rstd * gv.x + bev.x;
    o.y = (v[c * 4 + 1] - mean) * rstd * gv.y + bev.y;
    o.z = (v[c * 4 + 2] - mean) * rstd * gv.z + bev.z;
    o.w = (v[c * 4 + 3] - mean) * rstd * gv.w + bev.w;
    *(float4*)(hr + idx) = o;
  }
}

extern "C" void kernel_launch(void* const* d_in, const int* in_sizes, int n_in,
                              void* d_out, int out_size, void* d_ws, size_t ws_size,
                              hipStream_t stream) {
  const float* x      = (const float*)d_in[0];  // [4,2048,4096]
  const float* w      = (const float*)d_in[1];  // [4096,4096]
  const float* iscale = (const float*)d_in[2];  // [4096]
  const float* oscale = (const float*)d_in[3];  // [4096]
  const float* bias   = (const float*)d_in[4];  // [4096]
  const float* gamma  = (const float*)d_in[5];  // [4096]
  const float* beta   = (const float*)d_in[6];  // [4096]
  float* out = (float*)d_out;                   // [8192,4096] f32

  __bf16* Abf = (__bf16*)d_ws;                                   // 67 MB
  __bf16* Wbf = (__bf16*)((char*)d_ws + (size_t)GM * GK * 2);    // 33.5 MB

  // allow >64KB dynamic LDS (idempotent; immediate API, not graph-captured)
  (void)hipFuncSetAttribute((const void*)gemm_bt,
                            hipFuncAttributeMaxDynamicSharedMemorySize, LDS_BYTES);

  prep_x_kernel<<<(GM * GK) / (256 * 8), 256, 0, stream>>>(x, iscale, Abf);
  prep_w_kernel<<<(GN * GK) / (256 * 8), 256, 0, stream>>>(w, Wbf);
  gemm_bt<<<(GM / BM) * (GN / BN), 512, LDS_BYTES, stream>>>(Abf, Wbf, out);
  ln_fuse<<<GM, 256, 0, stream>>>(out, oscale, bias, gamma, beta);
}